// Round 1
// baseline (1017.752 us; speedup 1.0000x reference)
//
#include <hip/hip_runtime.h>

// Problem constants (static per reference)
#define NHEAD 8
#define NPOINT 4
#define NLVL 6
#define CDIM 256
#define BSZ 8
#define NQRY 4096
#define NVAL 10752

// ---------------- fp32 tiled GEMM, K fixed = 256 -------------------------
// C[M,N] = (A (+A2)) @ B + bias (+resid). A row-major [M,256], B row-major [256,N].
constexpr int BM = 128, BN = 64, BK = 16, TM = 8, TN = 4;

__global__ __launch_bounds__(256) void gemm_k256(
    const float* __restrict__ A, const float* __restrict__ A2,
    const float* __restrict__ B, const float* __restrict__ bias,
    const float* __restrict__ resid, float* __restrict__ Cmat,
    int M, int N)
{
    __shared__ float As[BK][BM + 4];
    __shared__ float Bs[BK][BN + 4];
    const int K = 256;
    const int tid = threadIdx.x;
    const long bm = (long)blockIdx.y * BM;
    const int bn = blockIdx.x * BN;
    const int tr = (tid >> 4) * TM;   // 0..120
    const int tc = (tid & 15) * TN;   // 0..60
    const int arow = tid >> 1;        // 0..127
    const int acol = (tid & 1) * 8;   // 0 or 8
    const int brow = tid >> 4;        // 0..15
    const int bcol = (tid & 15) * 4;  // 0..60

    float acc[TM][TN] = {};
    const float* Abase = A + (bm + arow) * K + acol;
    const float* A2base = A2 ? A2 + (bm + arow) * K + acol : nullptr;
    const float* Bbase = B + (long)brow * N + bn + bcol;

    for (int k0 = 0; k0 < K; k0 += BK) {
        float4 a0 = *(const float4*)(Abase + k0);
        float4 a1 = *(const float4*)(Abase + k0 + 4);
        if (A2base) {
            float4 t0 = *(const float4*)(A2base + k0);
            float4 t1 = *(const float4*)(A2base + k0 + 4);
            a0.x += t0.x; a0.y += t0.y; a0.z += t0.z; a0.w += t0.w;
            a1.x += t1.x; a1.y += t1.y; a1.z += t1.z; a1.w += t1.w;
        }
        As[acol + 0][arow] = a0.x; As[acol + 1][arow] = a0.y;
        As[acol + 2][arow] = a0.z; As[acol + 3][arow] = a0.w;
        As[acol + 4][arow] = a1.x; As[acol + 5][arow] = a1.y;
        As[acol + 6][arow] = a1.z; As[acol + 7][arow] = a1.w;
        float4 bv4 = *(const float4*)(Bbase + (long)k0 * N);
        *(float4*)&Bs[brow][bcol] = bv4;
        __syncthreads();
#pragma unroll
        for (int kk = 0; kk < BK; ++kk) {
            float4 av0 = *(const float4*)&As[kk][tr];
            float4 av1 = *(const float4*)&As[kk][tr + 4];
            float4 bv  = *(const float4*)&Bs[kk][tc];
            float a_[TM] = {av0.x, av0.y, av0.z, av0.w, av1.x, av1.y, av1.z, av1.w};
            float b_[TN] = {bv.x, bv.y, bv.z, bv.w};
#pragma unroll
            for (int i = 0; i < TM; ++i)
#pragma unroll
                for (int j = 0; j < TN; ++j)
                    acc[i][j] += a_[i] * b_[j];
        }
        __syncthreads();
    }

    float4 bias4 = *(const float4*)(bias + bn + tc);
#pragma unroll
    for (int i = 0; i < TM; ++i) {
        long row = bm + tr + i;
        float4 r;
        r.x = acc[i][0] + bias4.x;
        r.y = acc[i][1] + bias4.y;
        r.z = acc[i][2] + bias4.z;
        r.w = acc[i][3] + bias4.w;
        if (resid) {
            float4 q4 = *(const float4*)(resid + row * N + bn + tc);
            r.x += q4.x; r.y += q4.y; r.z += q4.z; r.w += q4.w;
        }
        *(float4*)(Cmat + row * N + bn + tc) = r;
    }
}

// ---------------- deformable sampling --------------------------------------
// One block (256 thr) per (b,q). Lane layout: d = tid&31 (channel), h = tid>>5.
// v layout: [b][pos][h*32+d] (same as value), off row [h][l][p][2], attn row [h][l*4+p].
__global__ __launch_bounds__(256) void ms_sample(
    const float* __restrict__ v,
    const float* __restrict__ off,
    const float* __restrict__ attnl,
    const float* __restrict__ refp,
    float* __restrict__ outi)
{
    __shared__ float s_off[NHEAD * NLVL * NPOINT * 2];  // 384
    __shared__ float s_at[NHEAD * NLVL * NPOINT];       // 192
    __shared__ float s_ref[NLVL * 2];                   // 12
    const int bq = blockIdx.x;          // 0..32767
    const int b = bq >> 12;             // / 4096
    const int tid = threadIdx.x;
    {
        const float* o = off + (long)bq * 384;
        s_off[tid] = o[tid];
        if (tid < 128) s_off[256 + tid] = o[256 + tid];
        const float* a = attnl + (long)bq * 192;
        if (tid < 192) s_at[tid] = a[tid];
        if (tid < 12) s_ref[tid] = refp[(long)bq * 12 + tid];
    }
    __syncthreads();

    const int d = tid & 31;
    const int h = tid >> 5;
    const float* sat = s_at + h * 24;
    float mx = sat[0];
#pragma unroll
    for (int i = 1; i < 24; ++i) mx = fmaxf(mx, sat[i]);
    float den = 0.f;
#pragma unroll
    for (int i = 0; i < 24; ++i) den += __expf(sat[i] - mx);
    const float inv = 1.0f / den;

    const float* vb = v + (long)b * NVAL * CDIM + h * 32 + d;
    float acc = 0.f;
    const int Hs[NLVL]  = {64, 32, 16, 64, 32, 16};
    const int S0s[NLVL] = {0, 4096, 5120, 5376, 9472, 10496};
#pragma unroll
    for (int l = 0; l < NLVL; ++l) {
        const int Hl = Hs[l], Wl = Hs[l];            // square levels
        const float rW = 1.0f / (float)Wl;           // power of two: exact
        const float rH = 1.0f / (float)Hl;
        const float* vl = vb + (long)S0s[l] * CDIM;
        const float rx = s_ref[l * 2 + 0], ry = s_ref[l * 2 + 1];
#pragma unroll
        for (int p = 0; p < NPOINT; ++p) {
            const float aw = __expf(sat[l * 4 + p] - mx) * inv;
            const float ox = s_off[((h * NLVL + l) * NPOINT + p) * 2 + 0];
            const float oy = s_off[((h * NLVL + l) * NPOINT + p) * 2 + 1];
            const float x = (rx + ox * rW) * (float)Wl - 0.5f;
            const float y = (ry + oy * rH) * (float)Hl - 0.5f;
            const float xf = floorf(x), yf = floorf(y);
            const int x0 = (int)xf, y0 = (int)yf;
            const float lx = x - xf, ly = y - yf;
            const float w00 = (1.f - lx) * (1.f - ly);
            const float w01 = lx * (1.f - ly);
            const float w10 = (1.f - lx) * ly;
            const float w11 = lx * ly;
            const int x0c = min(max(x0, 0), Wl - 1);
            const int x1c = min(max(x0 + 1, 0), Wl - 1);
            const int y0c = min(max(y0, 0), Hl - 1);
            const int y1c = min(max(y0 + 1, 0), Hl - 1);
            const bool vx0 = (x0 >= 0) & (x0 < Wl);
            const bool vx1 = (x0 + 1 >= 0) & (x0 + 1 < Wl);
            const bool vy0 = (y0 >= 0) & (y0 < Hl);
            const bool vy1 = (y0 + 1 >= 0) & (y0 + 1 < Hl);
            const float g00 = (vx0 && vy0) ? vl[(long)(y0c * Wl + x0c) * CDIM] : 0.f;
            const float g01 = (vx1 && vy0) ? vl[(long)(y0c * Wl + x1c) * CDIM] : 0.f;
            const float g10 = (vx0 && vy1) ? vl[(long)(y1c * Wl + x0c) * CDIM] : 0.f;
            const float g11 = (vx1 && vy1) ? vl[(long)(y1c * Wl + x1c) * CDIM] : 0.f;
            acc += aw * (w00 * g00 + w01 * g01 + w10 * g10 + w11 * g11);
        }
    }
    outi[(long)bq * CDIM + tid] = acc;  // channel = h*32+d == tid
}

// ---------------- launch ---------------------------------------------------
extern "C" void kernel_launch(void* const* d_in, const int* in_sizes, int n_in,
                              void* d_out, int out_size, void* d_ws, size_t ws_size,
                              hipStream_t stream) {
    const float* query     = (const float*)d_in[0];
    const float* query_pos = (const float*)d_in[1];
    const float* value     = (const float*)d_in[2];
    const float* refp      = (const float*)d_in[3];
    // d_in[4] = spatial_shapes (static, hard-coded)
    const float* W_off  = (const float*)d_in[5];
    const float* b_off  = (const float*)d_in[6];
    const float* W_attn = (const float*)d_in[7];
    const float* b_attn = (const float*)d_in[8];
    const float* W_val  = (const float*)d_in[9];
    const float* b_val  = (const float*)d_in[10];
    const float* W_out  = (const float*)d_in[11];
    const float* b_out  = (const float*)d_in[12];
    float* out = (float*)d_out;

    float* ws = (float*)d_ws;
    float* v_ws   = ws;                                  // 86016*256
    float* off_ws = v_ws + (long)86016 * 256;            // 32768*384
    float* at_ws  = off_ws + (long)32768 * 384;          // 32768*192
    float* interm = at_ws + (long)32768 * 192;           // 32768*256

    const int MV = BSZ * NVAL;   // 86016
    const int MQ = BSZ * NQRY;   // 32768

    // v = value @ W_val + b_val
    gemm_k256<<<dim3(CDIM / BN, MV / BM), 256, 0, stream>>>(
        value, nullptr, W_val, b_val, nullptr, v_ws, MV, CDIM);
    // off = (query+query_pos) @ W_off + b_off
    gemm_k256<<<dim3(384 / BN, MQ / BM), 256, 0, stream>>>(
        query, query_pos, W_off, b_off, nullptr, off_ws, MQ, 384);
    // attn logits = (query+query_pos) @ W_attn + b_attn
    gemm_k256<<<dim3(192 / BN, MQ / BM), 256, 0, stream>>>(
        query, query_pos, W_attn, b_attn, nullptr, at_ws, MQ, 192);
    // deformable sampling
    ms_sample<<<MQ, 256, 0, stream>>>(v_ws, off_ws, at_ws, refp, interm);
    // out = interm @ W_out + b_out + query
    gemm_k256<<<dim3(CDIM / BN, MQ / BM), 256, 0, stream>>>(
        interm, nullptr, W_out, b_out, query, out, MQ, CDIM);
}